// Round 1
// baseline (216.325 us; speedup 1.0000x reference)
//
#include <hip/hip_runtime.h>
#include <math.h>

// TransformLoss on MI355X.
// Math reduction: per row, with d1 = init_img - next_img, d2 = init_unclip - pred_unclip:
//   A=sum d1^2, C=sum d2^2, AB=sum d1*d2, S1=sum d1, S2=sum d2
//   cos = clip(AB/(sqrt(A)sqrt(C)),-1,1); sin_a = sqrt(1-cos^2); cm1 = cos-1
//   k = AB/A; W = C - AB*k; rA=1/sqrt(A); rW=1/sqrt(W)
//   s1 = S1*rA; s2 = (S2 - S1*k)*rW
//   p = cm1*s1 - sin_a*s2; q = sin_a*s1 + cm1*s2
//   u[d] = d1[d]*(p*rA - q*k*rW) + d2[d]*(q*rW)
//   loss_u[d] = 0.5 * nan_to_num( sum_rows(mask * u^2) / cnt )
//   mse[d]    = 0.5 * mean_rows( (d1-d2)^2 )
// Memory-bound: 201.3 MB single pass. One wave per row; 5-value butterfly reduce.

constexpr int D      = 768;
constexpr int B_ROWS = 16384;
constexpr int BDIM   = 256;   // 4 waves / block
constexpr int NBLK   = 512;   // 2048 waves -> 8 rows each

// ws layout: [0..767] acc_u, [768..1535] acc_mse, [1536] cnt
__global__ void zero_ws_kernel(float* __restrict__ ws, int n) {
    int i = blockIdx.x * blockDim.x + threadIdx.x;
    if (i < n) ws[i] = 0.0f;
}

__global__ __launch_bounds__(BDIM) void transform_loss_main(
    const float* __restrict__ g_init_img,
    const float* __restrict__ g_next_img,
    const float* __restrict__ g_init_unclip,
    const float* __restrict__ g_pred_unclip,
    float* __restrict__ ws)
{
    const int lane  = threadIdx.x & 63;
    const int wave  = threadIdx.x >> 6;
    const int gwave = blockIdx.x * (BDIM / 64) + wave;
    const int nwav  = gridDim.x * (BDIM / 64);

    float acc_u[3][4];
    float acc_m[3][4];
#pragma unroll
    for (int t = 0; t < 3; ++t)
#pragma unroll
        for (int j = 0; j < 4; ++j) { acc_u[t][j] = 0.f; acc_m[t][j] = 0.f; }
    float local_cnt = 0.f;

    for (int row = gwave; row < B_ROWS; row += nwav) {
        const size_t base = (size_t)row * D + (size_t)(lane * 4);
        float4 va[3], vb[3], vc[3], vd[3];
#pragma unroll
        for (int t = 0; t < 3; ++t) {
            va[t] = *(const float4*)(g_init_img    + base + t * 256);
            vb[t] = *(const float4*)(g_next_img    + base + t * 256);
            vc[t] = *(const float4*)(g_init_unclip + base + t * 256);
            vd[t] = *(const float4*)(g_pred_unclip + base + t * 256);
        }
        float d1[3][4], d2[3][4];
        float sA = 0.f, sC = 0.f, sAB = 0.f, sS1 = 0.f, sS2 = 0.f;
#pragma unroll
        for (int t = 0; t < 3; ++t) {
            const float a4[4] = {va[t].x, va[t].y, va[t].z, va[t].w};
            const float b4[4] = {vb[t].x, vb[t].y, vb[t].z, vb[t].w};
            const float c4[4] = {vc[t].x, vc[t].y, vc[t].z, vc[t].w};
            const float e4[4] = {vd[t].x, vd[t].y, vd[t].z, vd[t].w};
#pragma unroll
            for (int j = 0; j < 4; ++j) {
                float x = a4[j] - b4[j];
                float y = c4[j] - e4[j];
                d1[t][j] = x; d2[t][j] = y;
                sA  = fmaf(x, x, sA);
                sC  = fmaf(y, y, sC);
                sAB = fmaf(x, y, sAB);
                sS1 += x;
                sS2 += y;
            }
        }
        // 5-value wave64 butterfly reduction
#pragma unroll
        for (int m = 1; m < 64; m <<= 1) {
            sA  += __shfl_xor(sA,  m);
            sC  += __shfl_xor(sC,  m);
            sAB += __shfl_xor(sAB, m);
            sS1 += __shfl_xor(sS1, m);
            sS2 += __shfl_xor(sS2, m);
        }

        // mse accumulates over the FULL batch (no mask)
#pragma unroll
        for (int t = 0; t < 3; ++t)
#pragma unroll
            for (int j = 0; j < 4; ++j) {
                float dd = d1[t][j] - d2[t][j];
                acc_m[t][j] = fmaf(dd, dd, acc_m[t][j]);
            }

        const bool mask = (sA > 1e-16f);   // ||d1|| > 1e-8
        if (mask) {
            local_cnt += 1.f;
            float nA  = sqrtf(sA);
            float rA  = 1.f / nA;
            float nC  = sqrtf(sC);
            float cosang = sAB / (nA * nC);
            cosang = fminf(fmaxf(cosang, -1.f), 1.f);
            float sin_a = sqrtf(fmaxf(1.f - cosang * cosang, 0.f));
            float cm1 = cosang - 1.f;
            float k  = sAB / sA;
            float W  = sC - sAB * k;        // C - AB^2/A
            float rW = 1.f / sqrtf(W);
            float s1 = sS1 * rA;
            float s2 = (sS2 - sS1 * k) * rW;
            float p  = cm1 * s1 - sin_a * s2;
            float q  = sin_a * s1 + cm1 * s2;
            float c1 = p * rA - q * k * rW;
            float c2 = q * rW;
#pragma unroll
            for (int t = 0; t < 3; ++t)
#pragma unroll
                for (int j = 0; j < 4; ++j) {
                    float u = fmaf(d1[t][j], c1, d2[t][j] * c2);
                    acc_u[t][j] = fmaf(u, u, acc_u[t][j]);
                }
        }
    }

    // block-level reduction: LDS accumulate, then one global atomic pass
    __shared__ float sh[2 * D];
    __shared__ float shcnt;
    if (threadIdx.x == 0) shcnt = 0.f;
    for (int i = threadIdx.x; i < 2 * D; i += BDIM) sh[i] = 0.f;
    __syncthreads();
#pragma unroll
    for (int t = 0; t < 3; ++t)
#pragma unroll
        for (int j = 0; j < 4; ++j) {
            int dIdx = t * 256 + lane * 4 + j;
            atomicAdd(&sh[dIdx],     acc_u[t][j]);
            atomicAdd(&sh[D + dIdx], acc_m[t][j]);
        }
    if (lane == 0) atomicAdd(&shcnt, local_cnt);
    __syncthreads();
    for (int i = threadIdx.x; i < 2 * D; i += BDIM) atomicAdd(&ws[i], sh[i]);
    if (threadIdx.x == 0) atomicAdd(&ws[2 * D], shcnt);
}

__global__ void finalize_kernel(const float* __restrict__ ws, float* __restrict__ out) {
    int i = blockIdx.x * blockDim.x + threadIdx.x;
    if (i >= D) return;
    float cnt = fmaxf(ws[2 * D], 1.f);
    float lu = ws[i] / cnt;
    // jnp.nan_to_num(nan=0, posinf=0.1, neginf=-0.1)
    if (isnan(lu)) lu = 0.f;
    else if (isinf(lu)) lu = (lu > 0.f) ? 0.1f : -0.1f;
    out[i]     = 0.5f * lu;                          // WEIGHT_ROTE * loss_u
    out[D + i] = 0.5f * (ws[D + i] * (1.f / 16384.f)); // WEIGHT_MSE * (mse + 0)
}

extern "C" void kernel_launch(void* const* d_in, const int* in_sizes, int n_in,
                              void* d_out, int out_size, void* d_ws, size_t ws_size,
                              hipStream_t stream) {
    const float* init_img    = (const float*)d_in[0];
    const float* next_img    = (const float*)d_in[1];
    const float* init_unclip = (const float*)d_in[2];
    const float* pred_unclip = (const float*)d_in[3];
    float* ws  = (float*)d_ws;
    float* out = (float*)d_out;

    zero_ws_kernel<<<(2 * D + 1 + BDIM - 1) / BDIM, BDIM, 0, stream>>>(ws, 2 * D + 1);
    transform_loss_main<<<NBLK, BDIM, 0, stream>>>(init_img, next_img, init_unclip,
                                                   pred_unclip, ws);
    finalize_kernel<<<(D + BDIM - 1) / BDIM, BDIM, 0, stream>>>(ws, out);
}